// Round 1
// baseline (2792.457 us; speedup 1.0000x reference)
//
#include <hip/hip_runtime.h>

typedef __attribute__((ext_vector_type(4))) float f32x4;
typedef __attribute__((ext_vector_type(8))) short short8;

#define VOCAB 50257
#define HDIM 512
#define TLEN 1024

static __device__ __forceinline__ unsigned short f2bf(float f) {
  unsigned u = __float_as_uint(f);
  u += 0x7fffu + ((u >> 16) & 1u);           // round-to-nearest-even
  return (unsigned short)(u >> 16);
}

// ---------------------------------------------------------------- phase A: recurrence
// Single workgroup, 8 waves. W bf16 lives in the CU: 48 MFMA B-fragments/wave in
// VGPRs (192 regs/lane) + 16 fragments/wave in LDS (128 KB). h double-buffered in
// LDS as bf16; matvec = mfma_f32_16x16x32_bf16 with h broadcast as A (row 0 used).
// No inter-WG sync: the 3100-cy/step XCD-coherence round trip is gone.
__global__ __launch_bounds__(512, 2) void rnn_kernel(
    const int* __restrict__ tokens, const float* __restrict__ h0,
    const float* __restrict__ emb_table, const float* __restrict__ Whh,
    const float* __restrict__ bh, float* __restrict__ Hout)
{
  __shared__ short8 Wsp[8 * 16 * 64];                                   // 128 KB spill frags
  __shared__ __attribute__((aligned(16))) unsigned short hbuf[2][HDIM]; // 2 KB
  __shared__ int tokl[TLEN];                                            // 4 KB

  const int tid = threadIdx.x;
  const int lane = tid & 63;
  const int w = tid >> 6;        // wave 0..7 -> cols [w*64, w*64+64)
  const int g = lane >> 4;       // k-subgroup 0..3 within a 32-k chunk
  const int r = lane & 15;       // col-within-tile / mfma row index

  // ---- preload W fragments (B-operand layout: lane holds 8 consecutive k of col)
  short8 wf[4][12];              // [tile][kc] static-indexed, 192 VGPRs
#pragma unroll
  for (int tl = 0; tl < 4; ++tl) {
    const int col = w * 64 + tl * 16 + r;
#pragma unroll
    for (int kc = 0; kc < 16; ++kc) {
      const int kb = kc * 32 + g * 8;
      short8 v;
#pragma unroll
      for (int j = 0; j < 8; ++j)
        v[j] = (short)f2bf(Whh[(size_t)(kb + j) * HDIM + col]);
      if (kc < 12) wf[tl][kc] = v;
      else         Wsp[(w * 16 + (kc - 12) * 4 + tl) * 64 + lane] = v;
    }
  }

  // ---- h0 -> hbuf[0] (bf16 pairs), tokens -> LDS
  if (tid < 256) {
    unsigned pp = (unsigned)f2bf(h0[2 * tid]) | ((unsigned)f2bf(h0[2 * tid + 1]) << 16);
    *(unsigned*)&hbuf[0][2 * tid] = pp;
  }
  tokl[tid] = tokens[tid];
  tokl[tid + 512] = tokens[tid + 512];

  float bhv[4] = {0.f, 0.f, 0.f, 0.f};
  float e[4]   = {0.f, 0.f, 0.f, 0.f};
  if (g == 0) {
#pragma unroll
    for (int tl = 0; tl < 4; ++tl) bhv[tl] = bh[w * 64 + tl * 16 + r];
  }
  __syncthreads();
  {
    int tok0 = tokl[0];
    if (g == 0) {
#pragma unroll
      for (int tl = 0; tl < 4; ++tl)
        e[tl] = emb_table[(size_t)tok0 * HDIM + w * 64 + tl * 16 + r] + bhv[tl];
    }
  }

  // One step: z = e_t + h_{t-1} @ Whh ; h_t = tanh(z). Spill chunks (kc 12..15)
  // first so their ds_reads issue early; A reads exec-masked to row-0 lanes
  // (rows 1..15 of the mfma hold stale-but-finite bf16 -> outputs ignored).
#define RNN_STEP(T, PS, PD)                                                       \
  {                                                                               \
    f32x4 acc[4] = {{0.f,0.f,0.f,0.f},{0.f,0.f,0.f,0.f},                          \
                    {0.f,0.f,0.f,0.f},{0.f,0.f,0.f,0.f}};                         \
    const unsigned short* hb = hbuf[PS];                                          \
    short8 a = {};                                                                \
    _Pragma("unroll")                                                             \
    for (int kcp = 0; kcp < 4; ++kcp) {                                           \
      if (r == 0) a = *(const short8*)(hb + (12 + kcp) * 32 + g * 8);             \
      _Pragma("unroll")                                                           \
      for (int tl = 0; tl < 4; ++tl) {                                            \
        short8 b = Wsp[(w * 16 + kcp * 4 + tl) * 64 + lane];                      \
        acc[tl] = __builtin_amdgcn_mfma_f32_16x16x32_bf16(a, b, acc[tl], 0, 0, 0);\
      }                                                                           \
    }                                                                             \
    _Pragma("unroll")                                                             \
    for (int kc = 0; kc < 12; ++kc) {                                             \
      if (r == 0) a = *(const short8*)(hb + kc * 32 + g * 8);                     \
      _Pragma("unroll")                                                           \
      for (int tl = 0; tl < 4; ++tl)                                              \
        acc[tl] = __builtin_amdgcn_mfma_f32_16x16x32_bf16(a, wf[tl][kc],          \
                                                          acc[tl], 0, 0, 0);     \
    }                                                                             \
    if (g == 0) {                                                                 \
      int tokn = tokl[((T) + 1) & (TLEN - 1)];                                    \
      _Pragma("unroll")                                                           \
      for (int tl = 0; tl < 4; ++tl) {                                            \
        const int col = w * 64 + tl * 16 + r;                                     \
        float hv = tanhf(acc[tl][0] + e[tl]);                                     \
        Hout[(size_t)(T) * HDIM + col] = hv;                                      \
        hbuf[PD][col] = f2bf(hv);                                                 \
        e[tl] = emb_table[(size_t)tokn * HDIM + col] + bhv[tl];  /* prefetch */   \
      }                                                                           \
    }                                                                             \
    __syncthreads();                                                              \
  }

  for (int t = 0; t < TLEN; t += 2) {
    RNN_STEP(t, 0, 1)
    RNN_STEP(t + 1, 1, 0)
  }
#undef RNN_STEP
}

// ---------------------------------------------------------------- phase B: attention + X pack
__global__ __launch_bounds__(256) void attn_kernel(
    const float* __restrict__ Hall, unsigned short* __restrict__ Xbf)
{
  const int t = blockIdx.x;
  const int tid = threadIdx.x;
  const int lane = tid & 63;
  const int wave = tid >> 6;
  __shared__ float ht[HDIM];
  __shared__ float sc[TLEN];
  __shared__ float red[8];

  float h_a = Hall[(size_t)t * HDIM + tid];
  float h_b = Hall[(size_t)t * HDIM + tid + 256];
  ht[tid] = h_a; ht[tid + 256] = h_b;
  Xbf[(size_t)t * 1024 + tid] = f2bf(h_a);
  Xbf[(size_t)t * 1024 + tid + 256] = f2bf(h_b);
  __syncthreads();

  if (t == 0) {
    Xbf[512 + tid] = 0;
    Xbf[512 + tid + 256] = 0;
    return;
  }

  const f32x4* ht4 = (const f32x4*)ht;
  float lmax = -1e30f;
  for (int s = tid; s < t; s += 256) {
    const f32x4* hp = (const f32x4*)(Hall + (size_t)s * HDIM);
    float d = 0.f;
#pragma unroll 8
    for (int q = 0; q < HDIM / 4; ++q) {
      f32x4 a = hp[q]; f32x4 b = ht4[q];
      d += a.x * b.x + a.y * b.y + a.z * b.z + a.w * b.w;
    }
    sc[s] = d;
    lmax = fmaxf(lmax, d);
  }
  for (int off = 32; off > 0; off >>= 1) lmax = fmaxf(lmax, __shfl_down(lmax, off));
  if (lane == 0) red[wave] = lmax;
  __syncthreads();
  float m = fmaxf(fmaxf(red[0], red[1]), fmaxf(red[2], red[3]));
  __syncthreads();

  float lsum = 0.f;
  for (int s = tid; s < t; s += 256) {
    float ev = __expf(sc[s] - m);
    sc[s] = ev;
    lsum += ev;
  }
  for (int off = 32; off > 0; off >>= 1) lsum += __shfl_down(lsum, off);
  if (lane == 0) red[wave] = lsum;
  __syncthreads();
  float Z = red[0] + red[1] + red[2] + red[3];
  float inv = 1.0f / Z;

  float a0 = 0.f, a1 = 0.f;
#pragma unroll 4
  for (int s = 0; s < t; ++s) {
    float w = sc[s];
    a0 += w * Hall[(size_t)s * HDIM + tid];
    a1 += w * Hall[(size_t)s * HDIM + tid + 256];
  }
  Xbf[(size_t)t * 1024 + 512 + tid] = f2bf(a0 * inv);
  Xbf[(size_t)t * 1024 + 512 + tid + 256] = f2bf(a1 * inv);
}

// ---------------------------------------------------------------- W_c cast+transpose
__global__ __launch_bounds__(256) void convT_kernel(
    const float* __restrict__ Wc, unsigned short* __restrict__ WT)
{
  const int n0 = blockIdx.x * 64;
  const int k0 = blockIdx.y * 64;
  const int tid = threadIdx.x;
  __shared__ float tile[64][65];
  const int c = tid & 63;
  const int r = tid >> 6;
#pragma unroll
  for (int it = 0; it < 16; ++it) {
    int row = it * 4 + r;
    int n = n0 + c;
    tile[row][c] = (n < VOCAB) ? Wc[(size_t)(k0 + row) * VOCAB + n] : 0.f;
  }
  __syncthreads();
#pragma unroll
  for (int it = 0; it < 16; ++it) {
    int nr = it * 4 + r;
    int n = n0 + nr;
    if (n < VOCAB) WT[(size_t)n * 1024 + k0 + c] = f2bf(tile[c][nr]);
  }
}

// ---------------------------------------------------------------- phase C: MFMA GEMM (m97-style)
#define GLOBAL_AS __attribute__((address_space(1)))
#define LDS_AS __attribute__((address_space(3)))
#define ASYNC16(gsrc, ldst) \
  __builtin_amdgcn_global_load_lds((const GLOBAL_AS void*)(gsrc), (LDS_AS void*)(ldst), 16, 0, 0)

__global__ __launch_bounds__(256) void gemm_kernel(
    const unsigned short* __restrict__ Xbf, const unsigned short* __restrict__ WT,
    const float* __restrict__ bias, float* __restrict__ out)
{
  const int n0 = blockIdx.x * 128;
  const int m0 = blockIdx.y * 128;
  const int tid = threadIdx.x;
  const int lane = tid & 63;
  const int wave = tid >> 6;
  const int wm = wave >> 1, wn = wave & 1;
  const int r15 = lane & 15, kq = lane >> 4;

  __shared__ short As[128 * 64];     // 16 KB, slot s = (kc<<7)|row, 8 shorts/slot
  __shared__ short Bs[128 * 64];

  f32x4 acc[4][4] = {};

  for (int kb = 0; kb < 16; ++kb) {
#pragma unroll
    for (int j = 0; j < 4; ++j) {
      int slot = tid + 256 * j;        // 0..1023
      int kc = slot >> 7, row = slot & 127;
      ASYNC16(Xbf + (size_t)(m0 + row) * 1024 + kb * 64 + kc * 8, As + slot * 8);
      int n = n0 + row; n = (n < VOCAB) ? n : (VOCAB - 1);   // clamp; garbage cols unstored
      ASYNC16(WT + (size_t)n * 1024 + kb * 64 + kc * 8, Bs + slot * 8);
    }
    __syncthreads();                   // drains vmcnt (global_load_lds) too
#pragma unroll
    for (int s = 0; s < 2; ++s) {
      short8 af[4], bfr[4];
#pragma unroll
      for (int i = 0; i < 4; ++i)
        af[i] = *(const short8*)&As[(((s * 4 + kq) << 7) + wm * 64 + i * 16 + r15) * 8];
#pragma unroll
      for (int i = 0; i < 4; ++i)
        bfr[i] = *(const short8*)&Bs[(((s * 4 + kq) << 7) + wn * 64 + i * 16 + r15) * 8];
#pragma unroll
      for (int i = 0; i < 4; ++i)
#pragma unroll
        for (int jn = 0; jn < 4; ++jn)
          acc[i][jn] = __builtin_amdgcn_mfma_f32_16x16x32_bf16(af[i], bfr[jn], acc[i][jn], 0, 0, 0);
    }
    __syncthreads();
  }
  // epilogue: C/D layout col = lane&15, row = (lane>>4)*4 + reg
#pragma unroll
  for (int i = 0; i < 4; ++i) {
    int row = m0 + wm * 64 + i * 16 + kq * 4;
#pragma unroll
    for (int jn = 0; jn < 4; ++jn) {
      int col = n0 + wn * 64 + jn * 16 + r15;
      if (col < VOCAB) {
        float bv = bias[col];
#pragma unroll
        for (int rr = 0; rr < 4; ++rr)
          out[(size_t)(row + rr) * VOCAB + col] = acc[i][jn][rr] + bv;
      }
    }
  }
}

// ---------------------------------------------------------------- launch
extern "C" void kernel_launch(void* const* d_in, const int* in_sizes, int n_in,
                              void* d_out, int out_size, void* d_ws, size_t ws_size,
                              hipStream_t stream) {
  const int*   tokens   = (const int*)d_in[0];
  const float* h0       = (const float*)d_in[1];
  const float* emb      = (const float*)d_in[2];
  const float* Whh      = (const float*)d_in[3];
  const float* bh       = (const float*)d_in[4];
  const float* Wc       = (const float*)d_in[5];
  const float* bo       = (const float*)d_in[6];
  float* out = (float*)d_out;

  char* ws = (char*)d_ws;
  // ws layout (bytes): WT bf16 [50257*1024]   @ 0          (102,926,336)
  //                    H_all f32 [1024*512]   @ 102926336  (  2,097,152)
  //                    Xbf bf16 [1024*1024]   @ 105023488  (  2,097,152)
  unsigned short* WT   = (unsigned short*)(ws);
  float*          Hall = (float*)(ws + 102926336);
  unsigned short* Xbf  = (unsigned short*)(ws + 105023488);

  rnn_kernel<<<dim3(1), dim3(512), 0, stream>>>(tokens, h0, emb, Whh, bh, Hall);
  attn_kernel<<<dim3(TLEN), dim3(256), 0, stream>>>(Hall, Xbf);
  convT_kernel<<<dim3(786, 16), dim3(256), 0, stream>>>(Wc, WT);
  gemm_kernel<<<dim3(393, 8), dim3(256), 0, stream>>>(Xbf, WT, bo, out);
}